// Round 1
// baseline (8606.760 us; speedup 1.0000x reference)
//
#include <hip/hip_runtime.h>

#define NBLK 64
#define NTHR 256
#define SEQ  512
#define BAT  64
#define NINP 256
#define NHID 512
#define LDG  2048   // 4*NHID

typedef __attribute__((ext_vector_type(8))) short short8;
typedef __attribute__((ext_vector_type(4))) float f32x4;

static __device__ __forceinline__ unsigned short f2bf(float x) {
    return __builtin_bit_cast(unsigned short, (__bf16)x);
}
static __device__ __forceinline__ float sigm(float x)  { return 1.0f / (1.0f + __expf(-x)); }
static __device__ __forceinline__ float tanh_(float x) { return 2.0f / (1.0f + __expf(-2.0f * x)) - 1.0f; }

// d_ws layout: [0,4KB) flags (64 x 16 uints, one line per block), [4KB, 4KB+2*64KB) h double buffer (bf16)
__global__ __launch_bounds__(NTHR, 1)
void lstm_persistent(const float* __restrict__ x, const float* __restrict__ W,
                     const float* __restrict__ U, const float* __restrict__ bias,
                     float* __restrict__ out, unsigned short* __restrict__ hbuf,
                     unsigned int* __restrict__ flags)
{
    const int bk   = blockIdx.x;
    const int tid  = threadIdx.x;
    const int w    = tid >> 6;       // wave 0..3 -> M-tile (16 batch rows)
    const int lane = tid & 63;
    const int c16  = lane & 15;      // MFMA col / A-row-in-tile
    const int rq   = lane >> 4;      // quad 0..3

    // gate columns owned by this lane: nt=0 -> [i|f], nt=1 -> [g|o]
    const int col0 = (c16 >> 3) * NHID + (c16 & 7) + bk * 8;   // i (c16<8) or f (c16>=8)
    const int col1 = col0 + 2 * NHID;                           // g or o

    // ---- one-time: load U,W slices into register B-fragments (bf16) ----
    short8 ut[2][16];
#pragma unroll
    for (int kb = 0; kb < 16; ++kb) {
        const int k0 = kb * 32 + rq * 8;
        short8 v0, v1;
#pragma unroll
        for (int j = 0; j < 8; ++j) {
            v0[j] = (short)f2bf(U[(size_t)(k0 + j) * LDG + col0]);
            v1[j] = (short)f2bf(U[(size_t)(k0 + j) * LDG + col1]);
        }
        ut[0][kb] = v0; ut[1][kb] = v1;
    }
    short8 wt[2][8];
#pragma unroll
    for (int kb = 0; kb < 8; ++kb) {
        const int k0 = kb * 32 + rq * 8;
        short8 v0, v1;
#pragma unroll
        for (int j = 0; j < 8; ++j) {
            v0[j] = (short)f2bf(W[(size_t)(k0 + j) * LDG + col0]);
            v1[j] = (short)f2bf(W[(size_t)(k0 + j) * LDG + col1]);
        }
        wt[0][kb] = v0; wt[1][kb] = v1;
    }
    const float bias0 = bias[col0];
    const float bias1 = bias[col1];

    const int  arow  = w * 16 + c16;          // batch row for A fragments
    const bool lower = (c16 < 8);
    const bool up    = (c16 & 8);
    const int  hcol  = bk * 8 + (c16 & 7);
    float cst[4] = {0.f, 0.f, 0.f, 0.f};

    float* hout = out + (size_t)SEQ * BAT * NHID;
    float* cout_ = hout + BAT * NHID;

    for (int t = 0; t < SEQ; ++t) {
        // ---------- x @ W (independent of h -> runs in barrier slack) ----------
        f32x4 acc[2][4];
#pragma unroll
        for (int nt = 0; nt < 2; ++nt)
#pragma unroll
            for (int ch = 0; ch < 4; ++ch) acc[nt][ch] = (f32x4){0.f, 0.f, 0.f, 0.f};

        {
            const float* xr = x + ((size_t)t * BAT + arow) * NINP + rq * 8;
#pragma unroll
            for (int kb = 0; kb < 8; ++kb) {
                f32x4 a0 = *(const f32x4*)(xr + kb * 32);
                f32x4 a1 = *(const f32x4*)(xr + kb * 32 + 4);
                short8 xa;
#pragma unroll
                for (int j = 0; j < 4; ++j) {
                    xa[j]     = (short)f2bf(a0[j]);
                    xa[j + 4] = (short)f2bf(a1[j]);
                }
                const int ch = kb & 3;
                acc[0][ch] = __builtin_amdgcn_mfma_f32_16x16x32_bf16(xa, wt[0][kb], acc[0][ch], 0, 0, 0);
                acc[1][ch] = __builtin_amdgcn_mfma_f32_16x16x32_bf16(xa, wt[1][kb], acc[1][ch], 0, 0, 0);
            }
        }

        // ---------- wait until all blocks published h(t-1) ----------
        if (t > 0) {
            __syncthreads();
            if (tid < NBLK) {
                while (__hip_atomic_load(&flags[tid * 16], __ATOMIC_ACQUIRE,
                                         __HIP_MEMORY_SCOPE_AGENT) < (unsigned)t) { }
            }
            __syncthreads();
            __threadfence();   // acquire: invalidate L1/L2 so h reads are fresh
        }

        // ---------- h @ U ----------
        {
            const unsigned short* rh = hbuf + (size_t)((t + 1) & 1) * (BAT * NHID)
                                       + (size_t)arow * NHID + rq * 8;
#pragma unroll
            for (int kb = 0; kb < 16; ++kb) {
                short8 ah = *(const short8*)(rh + kb * 32);
                const int ch = kb & 3;
                acc[0][ch] = __builtin_amdgcn_mfma_f32_16x16x32_bf16(ah, ut[0][kb], acc[0][ch], 0, 0, 0);
                acc[1][ch] = __builtin_amdgcn_mfma_f32_16x16x32_bf16(ah, ut[1][kb], acc[1][ch], 0, 0, 0);
            }
        }

        f32x4 gif = acc[0][0] + acc[0][1] + acc[0][2] + acc[0][3];
        f32x4 ggo = acc[1][0] + acc[1][1] + acc[1][2] + acc[1][3];
#pragma unroll
        for (int j = 0; j < 4; ++j) { gif[j] += bias0; ggo[j] += bias1; }

        // exchange with partner lane (lane^8) so each lane sees all 4 gates
        f32x4 oif, ogo;
#pragma unroll
        for (int j = 0; j < 4; ++j) {
            oif[j] = __shfl_xor(gif[j], 8, 64);
            ogo[j] = __shfl_xor(ggo[j], 8, 64);
        }

        unsigned short* wh = hbuf + (size_t)(t & 1) * (BAT * NHID);
#pragma unroll
        for (int j = 0; j < 4; ++j) {
            const float gi = up ? oif[j] : gif[j];
            const float gf = up ? gif[j] : oif[j];
            const float gg = up ? ogo[j] : ggo[j];
            const float go = up ? ggo[j] : ogo[j];
            const float iv = sigm(gi);
            const float fv = sigm(gf);
            const float gv = tanh_(gg);
            const float ov = sigm(go);
            const float cn = fv * cst[j] + iv * gv;
            cst[j] = cn;
            const float hv = ov * tanh_(cn);
            if (lower) {
                const int batch = w * 16 + rq * 4 + j;
                wh[batch * NHID + hcol] = f2bf(hv);
                out[((size_t)t * BAT + batch) * NHID + hcol] = hv;
                if (t == SEQ - 1) {
                    hout[batch * NHID + hcol]  = hv;
                    cout_[batch * NHID + hcol] = cn;
                }
            }
        }

        // ---------- publish h(t) ----------
        if (t < SEQ - 1) {
            __threadfence();   // release: drain stores, write back L2 to device scope
            __syncthreads();
            if (tid == 0)
                __hip_atomic_store(&flags[bk * 16], (unsigned)(t + 1),
                                   __ATOMIC_RELEASE, __HIP_MEMORY_SCOPE_AGENT);
        }
    }
}

extern "C" void kernel_launch(void* const* d_in, const int* in_sizes, int n_in,
                              void* d_out, int out_size, void* d_ws, size_t ws_size,
                              hipStream_t stream) {
    (void)in_sizes; (void)n_in; (void)out_size; (void)ws_size;
    const float* x  = (const float*)d_in[0];
    const float* W  = (const float*)d_in[1];
    const float* U  = (const float*)d_in[2];
    const float* b  = (const float*)d_in[3];
    float* out = (float*)d_out;

    unsigned int*   flags = (unsigned int*)d_ws;
    unsigned short* hbuf  = (unsigned short*)((char*)d_ws + 4096);

    // zero flags + both h parity buffers (h(-1) = 0)
    hipMemsetAsync(d_ws, 0, 4096 + 2 * (size_t)BAT * NHID * sizeof(unsigned short), stream);
    hipLaunchKernelGGL(lstm_persistent, dim3(NBLK), dim3(NTHR), 0, stream,
                       x, W, U, b, out, hbuf, flags);
}

// Round 2
// 4335.729 us; speedup vs baseline: 1.9851x; 1.9851x over previous
//
#include <hip/hip_runtime.h>

#define NBLK 64
#define NTHR 256
#define SEQ  512
#define BAT  64
#define NINP 256
#define NHID 512
#define LDG  2048   // 4*NHID

typedef __attribute__((ext_vector_type(8))) short short8;
typedef __attribute__((ext_vector_type(4))) float f32x4;

static __device__ __forceinline__ unsigned short f2bf(float x) {
    return __builtin_bit_cast(unsigned short, (__bf16)x);
}
static __device__ __forceinline__ float sigm(float x)  { return 1.0f / (1.0f + __expf(-x)); }
static __device__ __forceinline__ float tanh_(float x) { return 2.0f / (1.0f + __expf(-2.0f * x)) - 1.0f; }

// d_ws layout: [0,4KB) flags (64 x 16 uints, one 64B line per block),
//              [4KB, 4KB+2*64KB) h double buffer (bf16)
// All cross-block traffic (h, flags) uses RELAXED agent-scope atomics ->
// sc1-coherent at L3, NO buffer_inv / buffer_wbl2 cache maintenance.
__global__ __launch_bounds__(NTHR, 1)
void lstm_persistent(const float* __restrict__ x, const float* __restrict__ W,
                     const float* __restrict__ U, const float* __restrict__ bias,
                     float* __restrict__ out, unsigned short* __restrict__ hbuf,
                     unsigned int* __restrict__ flags)
{
    const int bk   = blockIdx.x;
    const int tid  = threadIdx.x;
    const int w    = tid >> 6;       // wave 0..3 -> M-tile (16 batch rows)
    const int lane = tid & 63;
    const int c16  = lane & 15;      // MFMA col / A-row-in-tile
    const int rq   = lane >> 4;      // quad 0..3

    // gate columns owned by this lane: nt=0 -> [i|f], nt=1 -> [g|o]
    const int col0 = (c16 >> 3) * NHID + (c16 & 7) + bk * 8;   // i (c16<8) or f (c16>=8)
    const int col1 = col0 + 2 * NHID;                           // g or o

    // ---- one-time: load U,W slices into register B-fragments (bf16) ----
    short8 ut[2][16];
#pragma unroll
    for (int kb = 0; kb < 16; ++kb) {
        const int k0 = kb * 32 + rq * 8;
        short8 v0, v1;
#pragma unroll
        for (int j = 0; j < 8; ++j) {
            v0[j] = (short)f2bf(U[(size_t)(k0 + j) * LDG + col0]);
            v1[j] = (short)f2bf(U[(size_t)(k0 + j) * LDG + col1]);
        }
        ut[0][kb] = v0; ut[1][kb] = v1;
    }
    short8 wt[2][8];
#pragma unroll
    for (int kb = 0; kb < 8; ++kb) {
        const int k0 = kb * 32 + rq * 8;
        short8 v0, v1;
#pragma unroll
        for (int j = 0; j < 8; ++j) {
            v0[j] = (short)f2bf(W[(size_t)(k0 + j) * LDG + col0]);
            v1[j] = (short)f2bf(W[(size_t)(k0 + j) * LDG + col1]);
        }
        wt[0][kb] = v0; wt[1][kb] = v1;
    }
    const float bias0 = bias[col0];
    const float bias1 = bias[col1];

    const int  arow  = w * 16 + c16;          // batch row for A fragments
    const bool lower = (c16 < 8);
    const bool up    = (c16 & 8);
    const int  hcol  = bk * 8 + (c16 & 7);
    float cst[4] = {0.f, 0.f, 0.f, 0.f};

    float* hout  = out + (size_t)SEQ * BAT * NHID;
    float* cout_ = hout + BAT * NHID;

    for (int t = 0; t < SEQ; ++t) {
        // ---------- x @ W (independent of h -> overlaps other blocks' publish) ----------
        f32x4 acc[2][4];
#pragma unroll
        for (int nt = 0; nt < 2; ++nt)
#pragma unroll
            for (int ch = 0; ch < 4; ++ch) acc[nt][ch] = (f32x4){0.f, 0.f, 0.f, 0.f};

        {
            const float* xr = x + ((size_t)t * BAT + arow) * NINP + rq * 8;
#pragma unroll
            for (int kb = 0; kb < 8; ++kb) {
                f32x4 a0 = *(const f32x4*)(xr + kb * 32);
                f32x4 a1 = *(const f32x4*)(xr + kb * 32 + 4);
                short8 xa;
#pragma unroll
                for (int j = 0; j < 4; ++j) {
                    xa[j]     = (short)f2bf(a0[j]);
                    xa[j + 4] = (short)f2bf(a1[j]);
                }
                const int ch = kb & 3;
                acc[0][ch] = __builtin_amdgcn_mfma_f32_16x16x32_bf16(xa, wt[0][kb], acc[0][ch], 0, 0, 0);
                acc[1][ch] = __builtin_amdgcn_mfma_f32_16x16x32_bf16(xa, wt[1][kb], acc[1][ch], 0, 0, 0);
            }
        }

        if (t > 0) {
            // ---------- wait until all blocks published h(t-1) (relaxed poll, no inv) ----
            if (tid < NBLK) {
                while (__hip_atomic_load(&flags[tid * 16], __ATOMIC_RELAXED,
                                         __HIP_MEMORY_SCOPE_AGENT) < (unsigned)t) { }
            }
            __syncthreads();

            // ---------- h @ U (sc1-coherent loads straight from L3) ----------
            const unsigned long long* rh =
                (const unsigned long long*)(hbuf + (size_t)((t + 1) & 1) * (BAT * NHID)
                                            + (size_t)arow * NHID + rq * 8);
#pragma unroll
            for (int kb = 0; kb < 16; ++kb) {
                union { unsigned long long q[2]; short8 v; } u;
                u.q[0] = __hip_atomic_load(rh + kb * 8,     __ATOMIC_RELAXED, __HIP_MEMORY_SCOPE_AGENT);
                u.q[1] = __hip_atomic_load(rh + kb * 8 + 1, __ATOMIC_RELAXED, __HIP_MEMORY_SCOPE_AGENT);
                const int ch = kb & 3;
                acc[0][ch] = __builtin_amdgcn_mfma_f32_16x16x32_bf16(u.v, ut[0][kb], acc[0][ch], 0, 0, 0);
                acc[1][ch] = __builtin_amdgcn_mfma_f32_16x16x32_bf16(u.v, ut[1][kb], acc[1][ch], 0, 0, 0);
            }
        }
        // t == 0: h(-1) = 0, h@U contributes nothing -> skipped entirely.

        f32x4 gif = acc[0][0] + acc[0][1] + acc[0][2] + acc[0][3];
        f32x4 ggo = acc[1][0] + acc[1][1] + acc[1][2] + acc[1][3];
#pragma unroll
        for (int j = 0; j < 4; ++j) { gif[j] += bias0; ggo[j] += bias1; }

        // exchange with partner lane (lane^8) so each lane sees all 4 gates
        f32x4 oif, ogo;
#pragma unroll
        for (int j = 0; j < 4; ++j) {
            oif[j] = __shfl_xor(gif[j], 8, 64);
            ogo[j] = __shfl_xor(ggo[j], 8, 64);
        }

        float hv[4];
#pragma unroll
        for (int j = 0; j < 4; ++j) {
            const float gi = up ? oif[j] : gif[j];
            const float gf = up ? gif[j] : oif[j];
            const float gg = up ? ogo[j] : ggo[j];
            const float go = up ? ggo[j] : ogo[j];
            const float iv = sigm(gi);
            const float fv = sigm(gf);
            const float gv = tanh_(gg);
            const float ov = sigm(go);
            const float cn = fv * cst[j] + iv * gv;
            cst[j] = cn;
            hv[j] = ov * tanh_(cn);
        }

        // ---------- publish h(t): sc1 stores + ack + barrier + flag ----------
        if (t < SEQ - 1) {
            if (lower) {
                unsigned short* wh = hbuf + (size_t)(t & 1) * (BAT * NHID);
#pragma unroll
                for (int j = 0; j < 4; ++j) {
                    const int batch = w * 16 + rq * 4 + j;
                    __hip_atomic_store(&wh[batch * NHID + hcol], f2bf(hv[j]),
                                       __ATOMIC_RELAXED, __HIP_MEMORY_SCOPE_AGENT);
                }
            }
            asm volatile("s_waitcnt vmcnt(0)" ::: "memory");  // h stores acked at L3
            __syncthreads();                                   // all waves drained
            if (tid == 0)
                __hip_atomic_store(&flags[bk * 16], (unsigned)(t + 1),
                                   __ATOMIC_RELAXED, __HIP_MEMORY_SCOPE_AGENT);
        }

        // ---------- output stores (off the critical path) ----------
        if (lower) {
#pragma unroll
            for (int j = 0; j < 4; ++j) {
                const int batch = w * 16 + rq * 4 + j;
                out[((size_t)t * BAT + batch) * NHID + hcol] = hv[j];
                if (t == SEQ - 1) {
                    hout[batch * NHID + hcol]  = hv[j];
                    cout_[batch * NHID + hcol] = cst[j];
                }
            }
        }
    }
}

extern "C" void kernel_launch(void* const* d_in, const int* in_sizes, int n_in,
                              void* d_out, int out_size, void* d_ws, size_t ws_size,
                              hipStream_t stream) {
    (void)in_sizes; (void)n_in; (void)out_size; (void)ws_size;
    const float* x  = (const float*)d_in[0];
    const float* W  = (const float*)d_in[1];
    const float* U  = (const float*)d_in[2];
    const float* b  = (const float*)d_in[3];
    float* out = (float*)d_out;

    unsigned int*   flags = (unsigned int*)d_ws;
    unsigned short* hbuf  = (unsigned short*)((char*)d_ws + 4096);

    // zero flags only (t=0 skips h@U, so hbuf needs no init)
    hipMemsetAsync(d_ws, 0, 4096, stream);
    hipLaunchKernelGGL(lstm_persistent, dim3(NBLK), dim3(NTHR), 0, stream,
                       x, W, U, b, out, hbuf, flags);
}

// Round 3
// 3295.155 us; speedup vs baseline: 2.6119x; 1.3158x over previous
//
#include <hip/hip_runtime.h>

#define NBLK 64
#define NTHR 256
#define SEQ  512
#define BAT  64
#define NINP 256
#define NHID 512
#define LDG  2048   // 4*NHID

typedef __attribute__((ext_vector_type(8))) short short8;
typedef __attribute__((ext_vector_type(4))) float f32x4;
typedef __attribute__((ext_vector_type(4))) unsigned int uint4v;

static __device__ __forceinline__ unsigned short f2bf(float x) {
    return __builtin_bit_cast(unsigned short, (__bf16)x);
}
static __device__ __forceinline__ float sigm(float x)  { return 1.0f / (1.0f + __expf(-x)); }
static __device__ __forceinline__ float tanh_(float x) { return 2.0f / (1.0f + __expf(-2.0f * x)) - 1.0f; }

// L3-coherent 16B load (bypass L1+L2), issued without any implicit waitcnt.
template<int OFF>
static __device__ __forceinline__ void hload(short8& d, const unsigned short* p) {
    asm volatile("global_load_dwordx4 %0, %1, off offset:%2 sc0 sc1"
                 : "=v"(d) : "v"(p), "i"(OFF) : "memory");
}

// d_ws layout: [0,1KB) flags: 256 uints = (block,wave), [4KB, 4KB+2*64KB) h double buffer (bf16).
// All cross-block traffic goes through L3 via sc0+sc1 (no buffer_inv / wbl2 ever).
__global__ __launch_bounds__(NTHR, 1)
void lstm_persistent(const float* __restrict__ x, const float* __restrict__ W,
                     const float* __restrict__ U, const float* __restrict__ bias,
                     float* __restrict__ out, unsigned short* __restrict__ hbuf,
                     unsigned int* __restrict__ flags)
{
    const int bk   = blockIdx.x;
    const int tid  = threadIdx.x;
    const int w    = tid >> 6;       // wave 0..3 -> M-tile (16 batch rows)
    const int lane = tid & 63;
    const int c16  = lane & 15;      // MFMA col / A-row-in-tile
    const int rq   = lane >> 4;      // quad 0..3

    // gate columns owned by this lane: nt=0 -> [i|f], nt=1 -> [g|o]
    const int col0 = (c16 >> 3) * NHID + (c16 & 7) + bk * 8;   // i (c16<8) or f (c16>=8)
    const int col1 = col0 + 2 * NHID;                           // g or o

    // ---- one-time: load U,W slices into register B-fragments (bf16) ----
    short8 ut[2][16];
#pragma unroll
    for (int kb = 0; kb < 16; ++kb) {
        const int k0 = kb * 32 + rq * 8;
        short8 v0, v1;
#pragma unroll
        for (int j = 0; j < 8; ++j) {
            v0[j] = (short)f2bf(U[(size_t)(k0 + j) * LDG + col0]);
            v1[j] = (short)f2bf(U[(size_t)(k0 + j) * LDG + col1]);
        }
        ut[0][kb] = v0; ut[1][kb] = v1;
    }
    short8 wt[2][8];
#pragma unroll
    for (int kb = 0; kb < 8; ++kb) {
        const int k0 = kb * 32 + rq * 8;
        short8 v0, v1;
#pragma unroll
        for (int j = 0; j < 8; ++j) {
            v0[j] = (short)f2bf(W[(size_t)(k0 + j) * LDG + col0]);
            v1[j] = (short)f2bf(W[(size_t)(k0 + j) * LDG + col1]);
        }
        wt[0][kb] = v0; wt[1][kb] = v1;
    }
    const float bias0 = bias[col0];
    const float bias1 = bias[col1];

    const int  arow  = w * 16 + c16;          // batch row for A fragments
    const bool lower = (c16 < 8);
    const bool up    = (c16 & 8);
    const int  hcol  = bk * 8 + (c16 & 7);
    float cst[4] = {0.f, 0.f, 0.f, 0.f};

    float* hout  = out + (size_t)SEQ * BAT * NHID;
    float* cout_ = hout + BAT * NHID;

    for (int t = 0; t < SEQ; ++t) {
        // ---------- x @ W (independent of h -> overlaps other blocks' publish) ----------
        f32x4 acc[2][4];
#pragma unroll
        for (int nt = 0; nt < 2; ++nt)
#pragma unroll
            for (int ch = 0; ch < 4; ++ch) acc[nt][ch] = (f32x4){0.f, 0.f, 0.f, 0.f};

        {
            const float* xr = x + ((size_t)t * BAT + arow) * NINP + rq * 8;
#pragma unroll
            for (int kb = 0; kb < 8; ++kb) {
                f32x4 a0 = *(const f32x4*)(xr + kb * 32);
                f32x4 a1 = *(const f32x4*)(xr + kb * 32 + 4);
                short8 xa;
#pragma unroll
                for (int j = 0; j < 4; ++j) {
                    xa[j]     = (short)f2bf(a0[j]);
                    xa[j + 4] = (short)f2bf(a1[j]);
                }
                const int ch = kb & 3;
                acc[0][ch] = __builtin_amdgcn_mfma_f32_16x16x32_bf16(xa, wt[0][kb], acc[0][ch], 0, 0, 0);
                acc[1][ch] = __builtin_amdgcn_mfma_f32_16x16x32_bf16(xa, wt[1][kb], acc[1][ch], 0, 0, 0);
            }
        }

        if (t > 0) {
            // ---- wait until all 256 (block,wave) flags reach t: one coalesced dwordx4 poll ----
            if (tid < NBLK) {
                const unsigned int* fp = flags + tid * 4;
                uint4v f;
                do {
                    asm volatile("global_load_dwordx4 %0, %1, off sc0 sc1\n\t"
                                 "s_waitcnt vmcnt(0)"
                                 : "=v"(f) : "v"(fp) : "memory");
                } while (f.x < (unsigned)t || f.y < (unsigned)t ||
                         f.z < (unsigned)t || f.w < (unsigned)t);
            }
            __syncthreads();

            // ---- h @ U: 16 back-to-back 16B L3 loads, ONE wait, then MFMAs ----
            const unsigned short* rh = hbuf + (size_t)((t + 1) & 1) * (BAT * NHID)
                                       + (size_t)arow * NHID + rq * 8;
            short8 hreg[16];
            hload<0>  (hreg[0],  rh); hload<64> (hreg[1],  rh);
            hload<128>(hreg[2],  rh); hload<192>(hreg[3],  rh);
            hload<256>(hreg[4],  rh); hload<320>(hreg[5],  rh);
            hload<384>(hreg[6],  rh); hload<448>(hreg[7],  rh);
            hload<512>(hreg[8],  rh); hload<576>(hreg[9],  rh);
            hload<640>(hreg[10], rh); hload<704>(hreg[11], rh);
            hload<768>(hreg[12], rh); hload<832>(hreg[13], rh);
            hload<896>(hreg[14], rh); hload<960>(hreg[15], rh);
            asm volatile("s_waitcnt vmcnt(0)" ::: "memory");
            __builtin_amdgcn_sched_barrier(0);
#pragma unroll
            for (int kb = 0; kb < 16; ++kb) {
                const int ch = kb & 3;
                acc[0][ch] = __builtin_amdgcn_mfma_f32_16x16x32_bf16(hreg[kb], ut[0][kb], acc[0][ch], 0, 0, 0);
                acc[1][ch] = __builtin_amdgcn_mfma_f32_16x16x32_bf16(hreg[kb], ut[1][kb], acc[1][ch], 0, 0, 0);
            }
        }
        // t == 0: h(-1) = 0, h@U contributes nothing -> skipped entirely.

        f32x4 gif = acc[0][0] + acc[0][1] + acc[0][2] + acc[0][3];
        f32x4 ggo = acc[1][0] + acc[1][1] + acc[1][2] + acc[1][3];
#pragma unroll
        for (int j = 0; j < 4; ++j) { gif[j] += bias0; ggo[j] += bias1; }

        // exchange with partner lane (lane^8) so each lane sees all 4 gates
        f32x4 oif, ogo;
#pragma unroll
        for (int j = 0; j < 4; ++j) {
            oif[j] = __shfl_xor(gif[j], 8, 64);
            ogo[j] = __shfl_xor(ggo[j], 8, 64);
        }

        float hv[4];
#pragma unroll
        for (int j = 0; j < 4; ++j) {
            const float gi = up ? oif[j] : gif[j];
            const float gf = up ? gif[j] : oif[j];
            const float gg = up ? ogo[j] : ggo[j];
            const float go = up ? ggo[j] : ogo[j];
            const float iv = sigm(gi);
            const float fv = sigm(gf);
            const float gv = tanh_(gg);
            const float ov = sigm(go);
            const float cn = fv * cst[j] + iv * gv;
            cst[j] = cn;
            hv[j] = ov * tanh_(cn);
        }

        // ---------- publish h(t): per-wave stores + per-wave ack + per-wave flag ----------
        if (t < SEQ - 1) {
            if (lower) {
                unsigned short* wh = hbuf + (size_t)(t & 1) * (BAT * NHID);
#pragma unroll
                for (int j = 0; j < 4; ++j) {
                    const int batch = w * 16 + rq * 4 + j;
                    __hip_atomic_store(&wh[batch * NHID + hcol], f2bf(hv[j]),
                                       __ATOMIC_RELAXED, __HIP_MEMORY_SCOPE_AGENT);
                }
            }
            asm volatile("s_waitcnt vmcnt(0)" ::: "memory");  // this wave's h acked at L3
            if (lane == 0)
                __hip_atomic_store(&flags[bk * 4 + w], (unsigned)(t + 1),
                                   __ATOMIC_RELAXED, __HIP_MEMORY_SCOPE_AGENT);
        }

        // ---------- output stores (off the critical path) ----------
        if (lower) {
#pragma unroll
            for (int j = 0; j < 4; ++j) {
                const int batch = w * 16 + rq * 4 + j;
                out[((size_t)t * BAT + batch) * NHID + hcol] = hv[j];
                if (t == SEQ - 1) {
                    hout[batch * NHID + hcol]  = hv[j];
                    cout_[batch * NHID + hcol] = cst[j];
                }
            }
        }
    }
}

extern "C" void kernel_launch(void* const* d_in, const int* in_sizes, int n_in,
                              void* d_out, int out_size, void* d_ws, size_t ws_size,
                              hipStream_t stream) {
    (void)in_sizes; (void)n_in; (void)out_size; (void)ws_size;
    const float* x  = (const float*)d_in[0];
    const float* W  = (const float*)d_in[1];
    const float* U  = (const float*)d_in[2];
    const float* b  = (const float*)d_in[3];
    float* out = (float*)d_out;

    unsigned int*   flags = (unsigned int*)d_ws;
    unsigned short* hbuf  = (unsigned short*)((char*)d_ws + 4096);

    // zero flags only (t=0 skips h@U, so hbuf needs no init)
    hipMemsetAsync(d_ws, 0, 4096, stream);
    hipLaunchKernelGGL(lstm_persistent, dim3(NBLK), dim3(NTHR), 0, stream,
                       x, W, U, b, out, hbuf, flags);
}

// Round 6
// 2948.736 us; speedup vs baseline: 2.9188x; 1.1175x over previous
//
#include <hip/hip_runtime.h>

#define NBLK 64
#define NTHR 256
#define SEQ  512
#define BAT  64
#define NINP 256
#define NHID 512
#define LDG  2048   // 4*NHID

typedef __attribute__((ext_vector_type(8))) short short8;
typedef __attribute__((ext_vector_type(4))) float f32x4;
typedef __attribute__((ext_vector_type(4))) unsigned int uint4v;

static __device__ __forceinline__ unsigned short f2bf(float x) {
    return __builtin_bit_cast(unsigned short, (__bf16)x);
}
static __device__ __forceinline__ float sigm(float x)  { return 1.0f / (1.0f + __expf(-x)); }
static __device__ __forceinline__ float tanh_(float x) { return 2.0f / (1.0f + __expf(-2.0f * x)) - 1.0f; }

// L3-coherent 16B load, no implicit wait (caller drains vmcnt explicitly).
static __device__ __forceinline__ void hload(short8& d, const unsigned short* p) {
    asm volatile("global_load_dwordx4 %0, %1, off sc0 sc1" : "=v"(d) : "v"(p) : "memory");
}
// L3-coherent 16B store.
static __device__ __forceinline__ void hstore16(short8 v, unsigned short* p) {
    asm volatile("global_store_dwordx4 %0, %1, off sc0 sc1" :: "v"(p), "v"(v) : "memory");
}

// d_ws: [0,1KB) flags (256 uints, one per (block,wave)),
//       [4KB,4KB+2*64KB) h double buffer, block-major: [parity][block][batch][8 cols] bf16.
__global__ __launch_bounds__(NTHR, 1)
void lstm_persistent(const float* __restrict__ x, const float* __restrict__ W,
                     const float* __restrict__ U, const float* __restrict__ bias,
                     float* __restrict__ out, unsigned short* __restrict__ hbuf,
                     unsigned int* __restrict__ flags)
{
    __shared__ short8 lds_s[4 * 16];   // per-wave 256B transpose staging (wave-private)

    const int bk   = blockIdx.x;
    const int tid  = threadIdx.x;
    const int w    = tid >> 6;
    const int lane = tid & 63;
    const int c16  = lane & 15;
    const int rq   = lane >> 4;

    const int col0 = (c16 >> 3) * NHID + (c16 & 7) + bk * 8;   // i (c16<8) or f
    const int col1 = col0 + 2 * NHID;                           // g or o

    // ---- one-time: U,W slices into register B-fragments ----
    short8 ut[2][16];
#pragma unroll
    for (int kb = 0; kb < 16; ++kb) {
        const int k0 = kb * 32 + rq * 8;
        short8 v0, v1;
#pragma unroll
        for (int j = 0; j < 8; ++j) {
            v0[j] = (short)f2bf(U[(size_t)(k0 + j) * LDG + col0]);
            v1[j] = (short)f2bf(U[(size_t)(k0 + j) * LDG + col1]);
        }
        ut[0][kb] = v0; ut[1][kb] = v1;
    }
    short8 wt[2][8];
#pragma unroll
    for (int kb = 0; kb < 8; ++kb) {
        const int k0 = kb * 32 + rq * 8;
        short8 v0, v1;
#pragma unroll
        for (int j = 0; j < 8; ++j) {
            v0[j] = (short)f2bf(W[(size_t)(k0 + j) * LDG + col0]);
            v1[j] = (short)f2bf(W[(size_t)(k0 + j) * LDG + col1]);
        }
        wt[0][kb] = v0; wt[1][kb] = v1;
    }
    const float bias0 = bias[col0];
    const float bias1 = bias[col1];

    const int  arow  = w * 16 + c16;
    const bool lower = (c16 < 8);
    const bool up    = (c16 & 8);
    const int  hcol  = bk * 8 + (c16 & 7);
    float cst[4] = {0.f, 0.f, 0.f, 0.f};

    float* hout  = out + (size_t)SEQ * BAT * NHID;
    float* cout_ = hout + BAT * NHID;

    unsigned short* lds_w = (unsigned short*)&lds_s[w * 16];

    for (int t = 0; t < SEQ; ++t) {
        const int pR = (t + 1) & 1;   // parity to read (h(t-1))
        const int pW = t & 1;         // parity to write (h(t))

        // ---------- x @ W (plain compiler-visible loads; overlaps publish slack) ----------
        f32x4 acc[2][4];
#pragma unroll
        for (int nt = 0; nt < 2; ++nt)
#pragma unroll
            for (int ch = 0; ch < 4; ++ch) acc[nt][ch] = (f32x4){0.f, 0.f, 0.f, 0.f};

        {
            const float* xr = x + ((size_t)t * BAT + arow) * NINP + rq * 8;
#pragma unroll
            for (int kb = 0; kb < 8; ++kb) {
                f32x4 a0 = *(const f32x4*)(xr + kb * 32);
                f32x4 a1 = *(const f32x4*)(xr + kb * 32 + 4);
                short8 xa;
#pragma unroll
                for (int j = 0; j < 4; ++j) {
                    xa[j]     = (short)f2bf(a0[j]);
                    xa[j + 4] = (short)f2bf(a1[j]);
                }
                const int ch = kb & 3;
                acc[0][ch] = __builtin_amdgcn_mfma_f32_16x16x32_bf16(xa, wt[0][kb], acc[0][ch], 0, 0, 0);
                acc[1][ch] = __builtin_amdgcn_mfma_f32_16x16x32_bf16(xa, wt[1][kb], acc[1][ch], 0, 0, 0);
            }
        }

        if (t > 0) {
            // ---- poll all 256 (block,wave) flags: lanes of wave 0..3 with tid<64 ----
            if (tid < NBLK) {
                const unsigned int* fp = flags + tid * 4;
                uint4v f;
                do {
                    asm volatile("global_load_dwordx4 %0, %1, off sc0 sc1\n\t"
                                 "s_waitcnt vmcnt(0)"
                                 : "=v"(f) : "v"(fp) : "memory");
                } while (f[0] < (unsigned)t || f[1] < (unsigned)t ||
                         f[2] < (unsigned)t || f[3] < (unsigned)t);
            }
            __syncthreads();

            // ---- h @ U: 16 back-to-back full-line L3 loads (block-major), ONE wait ----
            const unsigned short* rb = hbuf + pR * 32768 + arow * 8;
            short8 hreg[16];
#pragma unroll
            for (int kb = 0; kb < 16; ++kb)
                hload(hreg[kb], rb + (kb * 4 + rq) * 512);
            asm volatile("s_waitcnt vmcnt(0)" ::: "memory");
            __builtin_amdgcn_sched_barrier(0);
#pragma unroll
            for (int kb = 0; kb < 16; ++kb) {
                const int ch = kb & 3;
                acc[0][ch] = __builtin_amdgcn_mfma_f32_16x16x32_bf16(hreg[kb], ut[0][kb], acc[0][ch], 0, 0, 0);
                acc[1][ch] = __builtin_amdgcn_mfma_f32_16x16x32_bf16(hreg[kb], ut[1][kb], acc[1][ch], 0, 0, 0);
            }
        }
        // t == 0: h(-1) = 0, h@U contributes nothing -> skipped entirely.

        f32x4 gif = acc[0][0] + acc[0][1] + acc[0][2] + acc[0][3];
        f32x4 ggo = acc[1][0] + acc[1][1] + acc[1][2] + acc[1][3];
#pragma unroll
        for (int j = 0; j < 4; ++j) { gif[j] += bias0; ggo[j] += bias1; }

        // ---- gate exchange + nonlinearity ----
        f32x4 oif, ogo;
#pragma unroll
        for (int j = 0; j < 4; ++j) {
            oif[j] = __shfl_xor(gif[j], 8, 64);
            ogo[j] = __shfl_xor(ggo[j], 8, 64);
        }
        float hv[4];
#pragma unroll
        for (int j = 0; j < 4; ++j) {
            const float gi = up ? oif[j] : gif[j];
            const float gf = up ? gif[j] : oif[j];
            const float gg = up ? ogo[j] : ggo[j];
            const float go = up ? ggo[j] : ogo[j];
            const float iv = sigm(gi);
            const float fv = sigm(gf);
            const float gv = tanh_(gg);
            const float ov = sigm(go);
            const float cn = fv * cst[j] + iv * gv;
            cst[j] = cn;
            hv[j] = ov * tanh_(cn);
        }

        // ---------- publish h(t): LDS micro-transpose -> packed full-line store ----------
        if (t < SEQ - 1) {
            if (lower) {
#pragma unroll
                for (int j = 0; j < 4; ++j)
                    lds_w[(rq * 4 + j) * 8 + c16] = f2bf(hv[j]);
            }
            if (lane < 16) {
                short8 hpk = lds_s[w * 16 + lane];   // compiler inserts lgkmcnt before use
                hstore16(hpk, hbuf + pW * 32768 + bk * 512 + (size_t)(w * 16 + lane) * 8);
            }
            asm volatile("s_waitcnt vmcnt(0)" ::: "memory");  // h store acked at L3
            if (lane == 0)
                __hip_atomic_store(&flags[bk * 4 + w], (unsigned)(t + 1),
                                   __ATOMIC_RELAXED, __HIP_MEMORY_SCOPE_AGENT);
        }

        // ---------- output stores (off the critical path) ----------
        if (lower) {
#pragma unroll
            for (int j = 0; j < 4; ++j) {
                const int batch = w * 16 + rq * 4 + j;
                out[((size_t)t * BAT + batch) * NHID + hcol] = hv[j];
                if (t == SEQ - 1) {
                    hout[batch * NHID + hcol]  = hv[j];
                    cout_[batch * NHID + hcol] = cst[j];
                }
            }
        }
    }
}

extern "C" void kernel_launch(void* const* d_in, const int* in_sizes, int n_in,
                              void* d_out, int out_size, void* d_ws, size_t ws_size,
                              hipStream_t stream) {
    (void)in_sizes; (void)n_in; (void)out_size; (void)ws_size;
    const float* x  = (const float*)d_in[0];
    const float* W  = (const float*)d_in[1];
    const float* U  = (const float*)d_in[2];
    const float* b  = (const float*)d_in[3];
    float* out = (float*)d_out;

    unsigned int*   flags = (unsigned int*)d_ws;
    unsigned short* hbuf  = (unsigned short*)((char*)d_ws + 4096);

    // zero flags (t=0 skips h@U, so hbuf needs no init; replay-safe)
    hipMemsetAsync(d_ws, 0, 4096, stream);
    hipLaunchKernelGGL(lstm_persistent, dim3(NBLK), dim3(NTHR), 0, stream,
                       x, W, U, b, out, hbuf, flags);
}